// Round 1
// baseline (83.595 us; speedup 1.0000x reference)
//
#include <hip/hip_runtime.h>
#include <hip/hip_bf16.h>

// ContrastiveLoss: loss = ( sum_{i,j: same&sim<1} (1-sim) + sum_{i,j: diff&sim>0.5} sim ) / n
// sim = E E^T, n=8192, d=512. Fused bf16-MFMA GEMM + mask/sum epilogue,
// upper-triangular tiles only (contribution is symmetric; diagonal self-pairs
// contribute 0 since sim_ii = ||e_i||^2 ~ 512 >= 1).

typedef __bf16 bf16x8 __attribute__((ext_vector_type(8)));
typedef __bf16 bf16x4 __attribute__((ext_vector_type(4)));
typedef float  f32x4  __attribute__((ext_vector_type(4)));

#define N_EMB 8192
#define D_EMB 512
#define BM    128
#define BK    32
#define TILES (N_EMB / BM)   // 64
#define MARGIN_F 0.5f

__device__ __forceinline__ void gll16(const __bf16* g, __bf16* l) {
    __builtin_amdgcn_global_load_lds(
        (const __attribute__((address_space(1))) void*)g,
        (__attribute__((address_space(3))) void*)l,
        16 /*bytes*/, 0 /*offset*/, 0 /*aux*/);
}

// fp32 -> bf16 conversion (one-time pre-pass; 24 MB traffic)
__global__ __launch_bounds__(256) void cvt_kernel(const float* __restrict__ in,
                                                  __bf16* __restrict__ out, int n4) {
    int i = blockIdx.x * blockDim.x + threadIdx.x;
    if (i < n4) {
        float4 v = reinterpret_cast<const float4*>(in)[i];
        bf16x4 o;
        o.x = (__bf16)v.x; o.y = (__bf16)v.y; o.z = (__bf16)v.z; o.w = (__bf16)v.w;
        reinterpret_cast<bf16x4*>(out)[i] = o;
    }
}

__global__ __launch_bounds__(256) void loss_kernel(const __bf16* __restrict__ E,
                                                   const int* __restrict__ label,
                                                   float* __restrict__ partials) {
    const int tc = blockIdx.x, tr = blockIdx.y;
    const int bid = tr * TILES + tc;
    if (tc < tr) {                       // lower triangle: no work
        if (threadIdx.x == 0) partials[bid] = 0.f;
        return;
    }

    __shared__ __bf16 As[BM * BK];       // 8 KB
    __shared__ __bf16 Bs[BM * BK];       // 8 KB
    __shared__ float  red[4];

    const int tid  = threadIdx.x;
    const int w    = tid >> 6, lane = tid & 63;
    const int wrow = w >> 1,   wcol = w & 1;     // 2x2 waves, each 64x64 out
    const int fr   = lane & 15;                  // fragment row(A)/col(B)/col(C)
    const int kg   = (lane >> 4) << 3;           // k-octet offset 0/8/16/24

    const int row0 = tr * BM, col0 = tc * BM;

    // lane-linear staging layout: tid -> row=tid/4, k-octet=(tid%4)*8
    // => LDS offset = wave_base + lane*16B, satisfying global_load_lds's
    // wave-uniform-dest + lane*size rule.
    const int ldrow = tid >> 2;
    const int ldcol = (tid & 3) << 3;
    const __bf16* gA = E + (size_t)(row0 + ldrow) * D_EMB + ldcol;
    const __bf16* gB = E + (size_t)(col0 + ldrow) * D_EMB + ldcol;
    __bf16* lA = &As[ldrow * BK + ldcol];
    __bf16* lB = &Bs[ldrow * BK + ldcol];

    f32x4 acc[4][4] = {};

    for (int k0 = 0; k0 < D_EMB; k0 += BK) {
        gll16(gA + k0,                lA);
        gll16(gA + k0 + 64 * D_EMB,   lA + 64 * BK);
        gll16(gB + k0,                lB);
        gll16(gB + k0 + 64 * D_EMB,   lB + 64 * BK);
        __syncthreads();   // drains vmcnt -> staged data visible

        bf16x8 a[4], b[4];
#pragma unroll
        for (int m = 0; m < 4; ++m)
            a[m] = *reinterpret_cast<const bf16x8*>(&As[(wrow * 64 + m * 16 + fr) * BK + kg]);
#pragma unroll
        for (int n = 0; n < 4; ++n)
            b[n] = *reinterpret_cast<const bf16x8*>(&Bs[(wcol * 64 + n * 16 + fr) * BK + kg]);
#pragma unroll
        for (int m = 0; m < 4; ++m)
#pragma unroll
            for (int n = 0; n < 4; ++n)
                acc[m][n] = __builtin_amdgcn_mfma_f32_16x16x32_bf16(a[m], b[n], acc[m][n], 0, 0, 0);
        __syncthreads();   // before next stage overwrites LDS
    }

    // Epilogue: C/D layout col = lane&15, row = (lane>>4)*4 + reg  [m89]
    float local = 0.f;
    int lj[4];
#pragma unroll
    for (int n = 0; n < 4; ++n) lj[n] = label[col0 + wcol * 64 + n * 16 + fr];
    const int rb = (lane >> 4) << 2;
#pragma unroll
    for (int m = 0; m < 4; ++m) {
#pragma unroll
        for (int r = 0; r < 4; ++r) {
            const int li = label[row0 + wrow * 64 + m * 16 + rb + r];
#pragma unroll
            for (int n = 0; n < 4; ++n) {
                const float s = acc[m][n][r];
                if (li == lj[n]) {
                    if (s < 1.0f) local += 1.0f - s;
                } else if (s > MARGIN_F) {
                    local += s;
                }
            }
        }
    }
    if (tr != tc) local *= 2.0f;   // off-diagonal tile counted for both (i,j),(j,i)

#pragma unroll
    for (int off = 32; off > 0; off >>= 1) local += __shfl_xor(local, off);
    if (lane == 0) red[w] = local;
    __syncthreads();
    if (tid == 0) partials[bid] = red[0] + red[1] + red[2] + red[3];
}

__global__ __launch_bounds__(256) void reduce_kernel(const float* __restrict__ partials,
                                                     float* __restrict__ out, int nb) {
    float s = 0.f;
    for (int i = threadIdx.x; i < nb; i += 256) s += partials[i];
#pragma unroll
    for (int off = 32; off > 0; off >>= 1) s += __shfl_xor(s, off);
    __shared__ float red[4];
    if ((threadIdx.x & 63) == 0) red[threadIdx.x >> 6] = s;
    __syncthreads();
    if (threadIdx.x == 0) {
        out[0] = (red[0] + red[1] + red[2] + red[3]) * (1.0f / (float)N_EMB);
        out[1] = 0.f;
        out[2] = 0.f;
    }
}

extern "C" void kernel_launch(void* const* d_in, const int* in_sizes, int n_in,
                              void* d_out, int out_size, void* d_ws, size_t ws_size,
                              hipStream_t stream) {
    const float* emb   = (const float*)d_in[0];
    const int*   label = (const int*)d_in[1];
    float*       out   = (float*)d_out;

    __bf16* Ebf     = (__bf16*)d_ws;                                    // 8 MB
    float*  partial = (float*)((char*)d_ws + (size_t)N_EMB * D_EMB * 2); // 16 KB

    const int n4 = N_EMB * D_EMB / 4;
    cvt_kernel<<<(n4 + 255) / 256, 256, 0, stream>>>(emb, Ebf, n4);

    dim3 grid(TILES, TILES);
    loss_kernel<<<grid, 256, 0, stream>>>(Ebf, label, partial);

    reduce_kernel<<<1, 256, 0, stream>>>(partial, out, TILES * TILES);
}

// Round 2
// 64.723 us; speedup vs baseline: 1.2916x; 1.2916x over previous
//
#include <hip/hip_runtime.h>
#include <hip/hip_bf16.h>

// ContrastiveLoss: loss = ( sum_{same & sim<1} (1-sim) + sum_{diff & sim>0.5} sim ) / n
// sim = E E^T, n=8192, d=512. bf16-MFMA GEMM fused with mask/sum epilogue.
// Upper-triangular tiles only (contribution symmetric; diagonal self-pairs = 0).
// R2: 512-thr blocks (8 waves, <=128 regs -> 16 waves/CU), explicit LDS dbuf
// with early-issued prefetch, 1 barrier/iter, triangular 1-D grid.

typedef __bf16 bf16x8 __attribute__((ext_vector_type(8)));
typedef __bf16 bf16x4 __attribute__((ext_vector_type(4)));
typedef float  f32x4  __attribute__((ext_vector_type(4)));

#define N_EMB 8192
#define D_EMB 512
#define BM    128
#define BK    32
#define KITER (D_EMB / BK)      // 16
#define TILES (N_EMB / BM)      // 64
#define NBLK  (TILES * (TILES + 1) / 2)   // 2080
#define MARGIN_F 0.5f

__device__ __forceinline__ void gll16(const __bf16* g, __bf16* l) {
    __builtin_amdgcn_global_load_lds(
        (const __attribute__((address_space(1))) void*)g,
        (__attribute__((address_space(3))) void*)l,
        16 /*bytes*/, 0 /*offset*/, 0 /*aux*/);
}

__global__ __launch_bounds__(256) void cvt_kernel(const float* __restrict__ in,
                                                  __bf16* __restrict__ out, int n4) {
    int i = blockIdx.x * blockDim.x + threadIdx.x;
    if (i < n4) {
        float4 v = reinterpret_cast<const float4*>(in)[i];
        bf16x4 o;
        o.x = (__bf16)v.x; o.y = (__bf16)v.y; o.z = (__bf16)v.z; o.w = (__bf16)v.w;
        reinterpret_cast<bf16x4*>(out)[i] = o;
    }
}

__global__ __launch_bounds__(512, 4) void loss_kernel(const __bf16* __restrict__ E,
                                                      const int* __restrict__ label,
                                                      float* __restrict__ partials) {
    // triangular decode: block t -> (tr, tc), tr <= tc, row-major upper tri
    const int t = blockIdx.x;
    int tr = (int)(64.5f - sqrtf(4160.25f - 2.0f * (float)t));
    // C(r) = rows before r = r*64 - r*(r-1)/2 ; correct float slop
    while ((tr + 1) * TILES - ((tr + 1) * tr) / 2 <= t) ++tr;
    while (tr * TILES - (tr * (tr - 1)) / 2 > t) --tr;
    const int tc = tr + (t - (tr * TILES - (tr * (tr - 1)) / 2));

    __shared__ __bf16 As[2][BM * BK];   // 2 x 8 KB
    __shared__ __bf16 Bs[2][BM * BK];   // 2 x 8 KB
    __shared__ float  red[8];

    const int tid  = threadIdx.x;
    const int w    = tid >> 6, lane = tid & 63;
    const int wrow = w >> 2,   wcol = w & 3;     // 2x4 waves, each 64x32 out
    const int fr   = lane & 15;                  // fragment row(A)/col(B)/col(C)
    const int kg   = (lane >> 4) << 3;           // k-octet 0/8/16/24

    const int row0 = tr * BM, col0 = tc * BM;

    // staging: tid -> row=tid/4, 16B slot=tid%4; LDS offset = tid*16B
    // (wave-uniform base + lane*16 rule satisfied)
    const int srow = tid >> 2;
    const int scol = (tid & 3) << 3;
    const __bf16* gA = E + (size_t)(row0 + srow) * D_EMB + scol;
    const __bf16* gB = E + (size_t)(col0 + srow) * D_EMB + scol;
    const int soff = tid << 3;   // element offset (8 bf16 = 16 B)

    f32x4 acc[4][2] = {};

    // prologue: stage tile 0
    gll16(gA, &As[0][soff]);
    gll16(gB, &Bs[0][soff]);
    __syncthreads();

    int cur = 0;
#pragma unroll 1
    for (int k = 0; k < KITER; ++k) {
        if (k + 1 < KITER) {        // issue next tile BEFORE compute
            gll16(gA + (k + 1) * BK, &As[cur ^ 1][soff]);
            gll16(gB + (k + 1) * BK, &Bs[cur ^ 1][soff]);
        }
        bf16x8 a[4], b[2];
#pragma unroll
        for (int m = 0; m < 4; ++m)
            a[m] = *reinterpret_cast<const bf16x8*>(&As[cur][(wrow * 64 + m * 16 + fr) * BK + kg]);
#pragma unroll
        for (int n = 0; n < 2; ++n)
            b[n] = *reinterpret_cast<const bf16x8*>(&Bs[cur][(wcol * 32 + n * 16 + fr) * BK + kg]);
#pragma unroll
        for (int m = 0; m < 4; ++m)
#pragma unroll
            for (int n = 0; n < 2; ++n)
                acc[m][n] = __builtin_amdgcn_mfma_f32_16x16x32_bf16(a[m], b[n], acc[m][n], 0, 0, 0);
        __syncthreads();   // drains vmcnt -> next buffer staged & everyone done reading cur
        cur ^= 1;
    }

    // Epilogue: C/D layout col = lane&15, row = (lane>>4)*4 + reg  [m89]
    float local = 0.f;
    int lj[2];
#pragma unroll
    for (int n = 0; n < 2; ++n) lj[n] = label[col0 + wcol * 32 + n * 16 + fr];
    const int rb = (lane >> 4) << 2;
#pragma unroll
    for (int m = 0; m < 4; ++m) {
#pragma unroll
        for (int r = 0; r < 4; ++r) {
            const int li = label[row0 + wrow * 64 + m * 16 + rb + r];
#pragma unroll
            for (int n = 0; n < 2; ++n) {
                const float s = acc[m][n][r];
                if (li == lj[n]) {
                    if (s < 1.0f) local += 1.0f - s;
                } else if (s > MARGIN_F) {
                    local += s;
                }
            }
        }
    }
    if (tr != tc) local *= 2.0f;   // off-diagonal tile stands for (i,j) and (j,i)

#pragma unroll
    for (int off = 32; off > 0; off >>= 1) local += __shfl_xor(local, off);
    if (lane == 0) red[w] = local;
    __syncthreads();
    if (tid == 0) {
        float s = 0.f;
#pragma unroll
        for (int i = 0; i < 8; ++i) s += red[i];
        partials[t] = s;
    }
}

__global__ __launch_bounds__(256) void reduce_kernel(const float* __restrict__ partials,
                                                     float* __restrict__ out, int nb) {
    float s = 0.f;
    for (int i = threadIdx.x; i < nb; i += 256) s += partials[i];
#pragma unroll
    for (int off = 32; off > 0; off >>= 1) s += __shfl_xor(s, off);
    __shared__ float red[4];
    if ((threadIdx.x & 63) == 0) red[threadIdx.x >> 6] = s;
    __syncthreads();
    if (threadIdx.x == 0) {
        out[0] = (red[0] + red[1] + red[2] + red[3]) * (1.0f / (float)N_EMB);
        out[1] = 0.f;
        out[2] = 0.f;
    }
}

extern "C" void kernel_launch(void* const* d_in, const int* in_sizes, int n_in,
                              void* d_out, int out_size, void* d_ws, size_t ws_size,
                              hipStream_t stream) {
    const float* emb   = (const float*)d_in[0];
    const int*   label = (const int*)d_in[1];
    float*       out   = (float*)d_out;

    __bf16* Ebf     = (__bf16*)d_ws;                                     // 8 MB
    float*  partial = (float*)((char*)d_ws + (size_t)N_EMB * D_EMB * 2); // 8.3 KB

    const int n4 = N_EMB * D_EMB / 4;
    cvt_kernel<<<(n4 + 255) / 256, 256, 0, stream>>>(emb, Ebf, n4);

    loss_kernel<<<NBLK, 512, 0, stream>>>(Ebf, label, partial);

    reduce_kernel<<<1, 256, 0, stream>>>(partial, out, NBLK);
}